// Round 2
// baseline (69.091 us; speedup 1.0000x reference)
//
#include <hip/hip_runtime.h>
#include <math.h>

#define A_N    1000
#define LQ_N   2048
#define C_N    3
#define H_N    10
#define HID_N  10000   // A_N * H_N
#define MID_N  5000
#define NPOS_N 1001
#define NOUT_N 2001
#define W2COLS 6001    // MID_N + NPOS_N

#define MV1_BLOCKS (MID_N / 4)                 // 1250, 4 waves/block, 1 row/wave
#define POS_BLOCKS ((NOUT_N + 3) / 4)          // 501
#define B_GRID     (MV1_BLOCKS + POS_BLOCKS)   // 1751

__device__ __forceinline__ float sigmoidf_(float x) { return 1.0f / (1.0f + expf(-x)); }

__device__ __forceinline__ float wave_reduce(float acc) {
    #pragma unroll
    for (int off = 32; off > 0; off >>= 1) acc += __shfl_down(acc, off, 64);
    return acc;
}

// Kernel A: last-timestep gather + 3 gate layers + tanh -> conc[A_N*H_N]
__global__ void __launch_bounds__(256) lstm_head(
    const float* __restrict__ quotes,
    const float* __restrict__ wih0, const float* __restrict__ bih0, const float* __restrict__ bhh0,
    const float* __restrict__ wih1, const float* __restrict__ bih1, const float* __restrict__ bhh1,
    const float* __restrict__ wih2, const float* __restrict__ bih2, const float* __restrict__ bhh2,
    float* __restrict__ conc)
{
    int a = blockIdx.x * blockDim.x + threadIdx.x;
    if (a >= A_N) return;

    const float* q = quotes + (size_t)a * LQ_N * C_N + (size_t)(LQ_N - 1) * C_N;
    float x0 = q[0], x1 = q[1], x2 = q[2];

    float g[40];
    float h[H_N];

    #pragma unroll
    for (int j = 0; j < 40; ++j)
        g[j] = x0 * wih0[j * 3 + 0] + x1 * wih0[j * 3 + 1] + x2 * wih0[j * 3 + 2]
             + bih0[j] + bhh0[j];
    #pragma unroll
    for (int k = 0; k < H_N; ++k) {
        float cc = sigmoidf_(g[k]) * tanhf(g[20 + k]);
        h[k] = sigmoidf_(g[30 + k]) * tanhf(cc);
    }

    #pragma unroll
    for (int j = 0; j < 40; ++j) {
        float s = bih1[j] + bhh1[j];
        #pragma unroll
        for (int k = 0; k < H_N; ++k) s += h[k] * wih1[j * 10 + k];
        g[j] = s;
    }
    float h2[H_N];
    #pragma unroll
    for (int k = 0; k < H_N; ++k) {
        float cc = sigmoidf_(g[k]) * tanhf(g[20 + k]);
        h2[k] = sigmoidf_(g[30 + k]) * tanhf(cc);
    }

    #pragma unroll
    for (int j = 0; j < 40; ++j) {
        float s = bih2[j] + bhh2[j];
        #pragma unroll
        for (int k = 0; k < H_N; ++k) s += h2[k] * wih2[j * 10 + k];
        g[j] = s;
    }
    #pragma unroll
    for (int k = 0; k < H_N; ++k) {
        float cc = sigmoidf_(g[k]) * tanhf(g[20 + k]);
        float hh = sigmoidf_(g[30 + k]) * tanhf(cc);
        conc[a * H_N + k] = tanhf(hh);
    }
}

// Kernel B: fused
//   blocks [0, MV1_BLOCKS):          lin = tanh(conc @ w1.T + b1), 1 wave/row, float4
//   blocks [MV1_BLOCKS, B_GRID):     partial[r] = b2[r] + w2[r, 5000:] . pos
__global__ void __launch_bounds__(256) fused_mv1_pos(
    const float* __restrict__ w1, const float* __restrict__ b1,
    const float* __restrict__ conc, float* __restrict__ lin,
    const float* __restrict__ w2, const float* __restrict__ b2,
    const float* __restrict__ pos, float* __restrict__ partial)
{
    int lane = threadIdx.x & 63;
    int wid  = threadIdx.x >> 6;

    if (blockIdx.x < MV1_BLOCKS) {
        int row = blockIdx.x * 4 + wid;            // < 5000 always
        const float4* rb = reinterpret_cast<const float4*>(w1 + (size_t)row * HID_N);
        const float4* v  = reinterpret_cast<const float4*>(conc);
        const int n4 = HID_N / 4;                  // 2500

        float acc0 = 0.0f, acc1 = 0.0f;
        int i = lane;
        for (; i + 64 < n4; i += 128) {
            float4 a0 = rb[i];      float4 c0 = v[i];
            float4 a1 = rb[i + 64]; float4 c1 = v[i + 64];
            acc0 += a0.x * c0.x + a0.y * c0.y + a0.z * c0.z + a0.w * c0.w;
            acc1 += a1.x * c1.x + a1.y * c1.y + a1.z * c1.z + a1.w * c1.w;
        }
        if (i < n4) {
            float4 a = rb[i]; float4 c = v[i];
            acc0 += a.x * c.x + a.y * c.y + a.z * c.z + a.w * c.w;
        }
        float acc = wave_reduce(acc0 + acc1);
        if (lane == 0) lin[row] = tanhf(acc + b1[row]);
    } else {
        int row = (blockIdx.x - MV1_BLOCKS) * 4 + wid;
        if (row >= NOUT_N) return;
        const float* wr = w2 + (size_t)row * W2COLS + MID_N;   // 1001 cols

        float acc = 0.0f;
        for (int j = lane; j < NPOS_N; j += 64)
            acc += wr[j] * pos[j];
        acc = wave_reduce(acc);
        if (lane == 0) partial[row] = acc + b2[row];
    }
}

// Kernel C: out[r] = partial[r] + w2[r, :5000] . lin    (1 wave/row, aligned float4 body)
__global__ void __launch_bounds__(256) mv2_main(
    const float* __restrict__ w2, const float* __restrict__ lin,
    const float* __restrict__ partial, float* __restrict__ out)
{
    int lane = threadIdx.x & 63;
    int wid  = threadIdx.x >> 6;
    int row  = blockIdx.x * 4 + wid;
    if (row >= NOUT_N) return;

    const float* wr = w2 + (size_t)row * W2COLS;
    const int p = (4 - (row & 3)) & 3;            // scalar prologue for 16B alignment
    const int n    = MID_N - p;
    const int n4   = n >> 2;
    const int tail = n & 3;

    float acc = 0.0f;
    if (lane < p) acc += wr[lane] * lin[lane];

    const float4* rb = reinterpret_cast<const float4*>(wr + p);
    float acc1 = 0.0f;
    int i = lane;
    for (; i + 64 < n4; i += 128) {
        float4 a0 = rb[i];
        float4 a1 = rb[i + 64];
        int j0 = p + 4 * i;
        int j1 = p + 4 * (i + 64);
        acc  += a0.x * lin[j0] + a0.y * lin[j0 + 1] + a0.z * lin[j0 + 2] + a0.w * lin[j0 + 3];
        acc1 += a1.x * lin[j1] + a1.y * lin[j1 + 1] + a1.z * lin[j1 + 2] + a1.w * lin[j1 + 3];
    }
    if (i < n4) {
        float4 a = rb[i];
        int j = p + 4 * i;
        acc += a.x * lin[j] + a.y * lin[j + 1] + a.z * lin[j + 2] + a.w * lin[j + 3];
    }
    if (lane < tail) {
        int j = p + 4 * n4 + lane;
        acc += wr[j] * lin[j];
    }

    float s = wave_reduce(acc + acc1);
    if (lane == 0) out[row] = partial[row] + s;
}

extern "C" void kernel_launch(void* const* d_in, const int* in_sizes, int n_in,
                              void* d_out, int out_size, void* d_ws, size_t ws_size,
                              hipStream_t stream)
{
    const float* quotes = (const float*)d_in[0];
    const float* pos    = (const float*)d_in[1];
    const float* wih0   = (const float*)d_in[2];
    const float* bih0   = (const float*)d_in[4];
    const float* bhh0   = (const float*)d_in[5];
    const float* wih1   = (const float*)d_in[6];
    const float* bih1   = (const float*)d_in[8];
    const float* bhh1   = (const float*)d_in[9];
    const float* wih2   = (const float*)d_in[10];
    const float* bih2   = (const float*)d_in[12];
    const float* bhh2   = (const float*)d_in[13];
    const float* w1     = (const float*)d_in[14];
    const float* b1     = (const float*)d_in[15];
    const float* w2     = (const float*)d_in[16];
    const float* b2     = (const float*)d_in[17];
    float* out = (float*)d_out;

    float* conc    = (float*)d_ws;        // HID_N
    float* lin     = conc + HID_N;        // MID_N
    float* partial = lin + MID_N;         // NOUT_N

    lstm_head<<<(A_N + 255) / 256, 256, 0, stream>>>(
        quotes, wih0, bih0, bhh0, wih1, bih1, bhh1, wih2, bih2, bhh2, conc);

    fused_mv1_pos<<<B_GRID, 256, 0, stream>>>(
        w1, b1, conc, lin, w2, b2, pos, partial);

    mv2_main<<<POS_BLOCKS, 256, 0, stream>>>(w2, lin, partial, out);
}

// Round 3
// 64.832 us; speedup vs baseline: 1.0657x; 1.0657x over previous
//
#include <hip/hip_runtime.h>
#include <math.h>

#define A_N    1000
#define LQ_N   2048
#define C_N    3
#define H_N    10
#define HID_N  10000   // A_N * H_N
#define MID_N  5000
#define NPOS_N 1001
#define NOUT_N 2001
#define W2COLS 6001    // MID_N + NPOS_N
#define VCAT_N 6004    // vcat padded to multiple of 4

__device__ __forceinline__ float sigmoidf_(float x) { return 1.0f / (1.0f + expf(-x)); }

__device__ __forceinline__ float wave_reduce(float acc) {
    #pragma unroll
    for (int off = 32; off > 0; off >>= 1) acc += __shfl_down(acc, off, 64);
    return acc;
}

// Kernel A: blocks 0-3: lstm head -> conc ; block 4: pos -> vcat[5000:], pad zeros
__global__ void __launch_bounds__(256) lstm_head(
    const float* __restrict__ quotes,
    const float* __restrict__ wih0, const float* __restrict__ bih0, const float* __restrict__ bhh0,
    const float* __restrict__ wih1, const float* __restrict__ bih1, const float* __restrict__ bhh1,
    const float* __restrict__ wih2, const float* __restrict__ bih2, const float* __restrict__ bhh2,
    const float* __restrict__ pos,
    float* __restrict__ conc, float* __restrict__ vcat)
{
    if (blockIdx.x == 4) {
        // copy position into vcat tail + zero the 3-float pad
        for (int j = threadIdx.x; j < NPOS_N; j += 256)
            vcat[MID_N + j] = pos[j];
        if (threadIdx.x < 3) vcat[W2COLS + threadIdx.x] = 0.0f;
        return;
    }

    int a = blockIdx.x * blockDim.x + threadIdx.x;
    if (a >= A_N) return;

    const float* q = quotes + (size_t)a * LQ_N * C_N + (size_t)(LQ_N - 1) * C_N;
    float x0 = q[0], x1 = q[1], x2 = q[2];

    float g[40];
    float h[H_N];

    #pragma unroll
    for (int j = 0; j < 40; ++j)
        g[j] = x0 * wih0[j * 3 + 0] + x1 * wih0[j * 3 + 1] + x2 * wih0[j * 3 + 2]
             + bih0[j] + bhh0[j];
    #pragma unroll
    for (int k = 0; k < H_N; ++k) {
        float cc = sigmoidf_(g[k]) * tanhf(g[20 + k]);
        h[k] = sigmoidf_(g[30 + k]) * tanhf(cc);
    }

    #pragma unroll
    for (int j = 0; j < 40; ++j) {
        float s = bih1[j] + bhh1[j];
        #pragma unroll
        for (int k = 0; k < H_N; ++k) s += h[k] * wih1[j * 10 + k];
        g[j] = s;
    }
    float h2[H_N];
    #pragma unroll
    for (int k = 0; k < H_N; ++k) {
        float cc = sigmoidf_(g[k]) * tanhf(g[20 + k]);
        h2[k] = sigmoidf_(g[30 + k]) * tanhf(cc);
    }

    #pragma unroll
    for (int j = 0; j < 40; ++j) {
        float s = bih2[j] + bhh2[j];
        #pragma unroll
        for (int k = 0; k < H_N; ++k) s += h2[k] * wih2[j * 10 + k];
        g[j] = s;
    }
    #pragma unroll
    for (int k = 0; k < H_N; ++k) {
        float cc = sigmoidf_(g[k]) * tanhf(g[20 + k]);
        float hh = sigmoidf_(g[30 + k]) * tanhf(cc);
        conc[a * H_N + k] = tanhf(hh);
    }
}

// Kernel B: lin(vcat[0:5000]) = tanh(conc @ w1.T + b1). 1 wave/row, 4-deep float4 ILP.
// 200 MB pure stream. 2500 float4 per row = 9*256 + 3*64 + 4.
__global__ void __launch_bounds__(256) mv1(
    const float* __restrict__ w1, const float* __restrict__ b1,
    const float* __restrict__ conc, float* __restrict__ vcat)
{
    int lane = threadIdx.x & 63;
    int wid  = threadIdx.x >> 6;
    int row  = blockIdx.x * 4 + wid;           // < 5000 always (grid = 1250)

    const float4* rb = reinterpret_cast<const float4*>(w1 + (size_t)row * HID_N);
    const float4* cv = reinterpret_cast<const float4*>(conc);

    float acc0 = 0.f, acc1 = 0.f, acc2 = 0.f, acc3 = 0.f;
    int i = lane;
    #pragma unroll 1
    for (int k = 0; k < 9; ++k, i += 256) {
        float4 a0 = rb[i];       float4 a1 = rb[i + 64];
        float4 a2 = rb[i + 128]; float4 a3 = rb[i + 192];
        float4 c0 = cv[i];       float4 c1 = cv[i + 64];
        float4 c2 = cv[i + 128]; float4 c3 = cv[i + 192];
        acc0 += a0.x * c0.x + a0.y * c0.y + a0.z * c0.z + a0.w * c0.w;
        acc1 += a1.x * c1.x + a1.y * c1.y + a1.z * c1.z + a1.w * c1.w;
        acc2 += a2.x * c2.x + a2.y * c2.y + a2.z * c2.z + a2.w * c2.w;
        acc3 += a3.x * c3.x + a3.y * c3.y + a3.z * c3.z + a3.w * c3.w;
    }
    // i = lane + 2304 ; remaining 196 float4 = 3*64 + 4
    {
        float4 a0 = rb[i];       float4 a1 = rb[i + 64];  float4 a2 = rb[i + 128];
        float4 c0 = cv[i];       float4 c1 = cv[i + 64];  float4 c2 = cv[i + 128];
        acc0 += a0.x * c0.x + a0.y * c0.y + a0.z * c0.z + a0.w * c0.w;
        acc1 += a1.x * c1.x + a1.y * c1.y + a1.z * c1.z + a1.w * c1.w;
        acc2 += a2.x * c2.x + a2.y * c2.y + a2.z * c2.z + a2.w * c2.w;
    }
    if (lane < 4) {
        float4 a = rb[2496 + lane];
        float4 c = cv[2496 + lane];
        acc3 += a.x * c.x + a.y * c.y + a.z * c.z + a.w * c.w;
    }

    float acc = wave_reduce((acc0 + acc1) + (acc2 + acc3));
    if (lane == 0) vcat[row] = tanhf(acc + b1[row]);
}

// Kernel C: out[r] = w2[r,:] . vcat + b2[r]. Full 6001-col row, aligned float4 body,
// scalar prologue/tail, 4-deep ILP. vcat gathers hit L1 (24 KB, shared by all waves).
__global__ void __launch_bounds__(256) mv2(
    const float* __restrict__ w2, const float* __restrict__ b2,
    const float* __restrict__ vcat, float* __restrict__ out)
{
    int lane = threadIdx.x & 63;
    int wid  = threadIdx.x >> 6;
    int row  = blockIdx.x * 4 + wid;
    if (row >= NOUT_N) return;

    const float* wr = w2 + (size_t)row * W2COLS;
    const int p    = (4 - (row & 3)) & 3;      // (row*6001) % 4 == row % 4
    const int n    = W2COLS - p;
    const int n4   = n >> 2;                   // ~1500
    const int tail = n & 3;

    float acc0 = 0.f, acc1 = 0.f, acc2 = 0.f, acc3 = 0.f;
    if (lane < p) acc0 += wr[lane] * vcat[lane];

    const float4* rb = reinterpret_cast<const float4*>(wr + p);
    int i = lane;
    #pragma unroll 1
    for (; i + 192 < n4; i += 256) {
        float4 a0 = rb[i];       float4 a1 = rb[i + 64];
        float4 a2 = rb[i + 128]; float4 a3 = rb[i + 192];
        int j0 = p + 4 * i, j1 = j0 + 256, j2 = j0 + 512, j3 = j0 + 768;
        acc0 += a0.x * vcat[j0] + a0.y * vcat[j0+1] + a0.z * vcat[j0+2] + a0.w * vcat[j0+3];
        acc1 += a1.x * vcat[j1] + a1.y * vcat[j1+1] + a1.z * vcat[j1+2] + a1.w * vcat[j1+3];
        acc2 += a2.x * vcat[j2] + a2.y * vcat[j2+1] + a2.z * vcat[j2+2] + a2.w * vcat[j2+3];
        acc3 += a3.x * vcat[j3] + a3.y * vcat[j3+1] + a3.z * vcat[j3+2] + a3.w * vcat[j3+3];
    }
    #pragma unroll 1
    for (; i < n4; i += 64) {
        float4 a = rb[i];
        int j = p + 4 * i;
        acc0 += a.x * vcat[j] + a.y * vcat[j+1] + a.z * vcat[j+2] + a.w * vcat[j+3];
    }
    if (lane < tail) {
        int j = p + 4 * n4 + lane;
        acc0 += wr[j] * vcat[j];
    }

    float s = wave_reduce((acc0 + acc1) + (acc2 + acc3));
    if (lane == 0) out[row] = s + b2[row];
}

extern "C" void kernel_launch(void* const* d_in, const int* in_sizes, int n_in,
                              void* d_out, int out_size, void* d_ws, size_t ws_size,
                              hipStream_t stream)
{
    const float* quotes = (const float*)d_in[0];
    const float* pos    = (const float*)d_in[1];
    const float* wih0   = (const float*)d_in[2];
    const float* bih0   = (const float*)d_in[4];
    const float* bhh0   = (const float*)d_in[5];
    const float* wih1   = (const float*)d_in[6];
    const float* bih1   = (const float*)d_in[8];
    const float* bhh1   = (const float*)d_in[9];
    const float* wih2   = (const float*)d_in[10];
    const float* bih2   = (const float*)d_in[12];
    const float* bhh2   = (const float*)d_in[13];
    const float* w1     = (const float*)d_in[14];
    const float* b1     = (const float*)d_in[15];
    const float* w2     = (const float*)d_in[16];
    const float* b2     = (const float*)d_in[17];
    float* out = (float*)d_out;

    float* vcat = (float*)d_ws;           // VCAT_N floats: [lin | pos | pad]
    float* conc = vcat + 6016;            // HID_N floats, 16B-aligned offset

    lstm_head<<<5, 256, 0, stream>>>(
        quotes, wih0, bih0, bhh0, wih1, bih1, bhh1, wih2, bih2, bhh2,
        pos, conc, vcat);

    mv1<<<MID_N / 4, 256, 0, stream>>>(w1, b1, conc, vcat);

    mv2<<<(NOUT_N + 3) / 4, 256, 0, stream>>>(w2, b2, vcat, out);
}